// Round 5
// baseline (515.884 us; speedup 1.0000x reference)
//
#include <hip/hip_runtime.h>
#include <cstdint>

// GraphNets block, bf16-MFMA, wave-private MLP (32 rows/wave) + CSR gather MP.
// mfma_f32_16x16x32_bf16: A lane l: row=l&15, k=(l>>4)*8+j ; B: col=l&15, same k
// C/D: col=lane&15, row=(lane>>4)*4+reg   [verified by v2/v3/v4 passes]

typedef short short8 __attribute__((ext_vector_type(8)));
typedef float f32x4 __attribute__((ext_vector_type(4)));

#define MFMA16(a, b, c) __builtin_amdgcn_mfma_f32_16x16x32_bf16(a, b, c, 0, 0, 0)

__device__ __forceinline__ short f2bf(float x) {
    union { __bf16 b; short s; } u; u.b = (__bf16)x; return u.s;
}

// ---------------------------------------------------------------------------
// Weight prep: fp32 [K][N] -> bf16 pre-swizzled B-fragments (frag kf*NF+nf,
// 1024B each, lane-contiguous). 208 frags.  (verified v2-v4)
// ---------------------------------------------------------------------------
__global__ __launch_bounds__(256)
void prep_weights(const float* __restrict__ We1, const float* __restrict__ We2,
                  const float* __restrict__ We3, const float* __restrict__ Wn1,
                  const float* __restrict__ Wn2, const float* __restrict__ Wn3,
                  char* __restrict__ out)
{
    const int fg = blockIdx.x * 4 + (threadIdx.x >> 6);
    if (fg >= 208) return;
    const int lane = threadIdx.x & 63;
    const float* W; int Ncols, f; size_t obase;
    if      (fg < 64)  { W = We1; Ncols = 128; f = fg;       obase = 0;      }
    else if (fg < 96)  { W = We2; Ncols = 128; f = fg - 64;  obase = 65536;  }
    else if (fg < 112) { W = We3; Ncols = 64;  f = fg - 96;  obase = 98304;  }
    else if (fg < 160) { W = Wn1; Ncols = 128; f = fg - 112; obase = 114688; }
    else if (fg < 192) { W = Wn2; Ncols = 128; f = fg - 160; obase = 163840; }
    else               { W = Wn3; Ncols = 64;  f = fg - 192; obase = 196608; }
    const int NF = Ncols >> 4;
    const int kf = f / NF, nf = f - kf * NF;
    const int k0 = kf * 32 + (lane >> 4) * 8;
    const int col = nf * 16 + (lane & 15);
    union { short s[8]; uint4 u; } pk;
#pragma unroll
    for (int j = 0; j < 8; ++j) pk.s[j] = f2bf(W[(size_t)(k0 + j) * Ncols + col]);
    *(uint4*)(out + obase + ((size_t)f * 64 + lane) * 16) = pk.u;
}

// ---------------------------------------------------------------------------
// CSR build: histogram -> 2-level exclusive scan -> fill.  (verified v4)
// ---------------------------------------------------------------------------
__global__ __launch_bounds__(256)
void hist_kernel(const int* __restrict__ dst, int* __restrict__ deg, int E)
{
    const int i = blockIdx.x * 256 + threadIdx.x;
    if (i < E) atomicAdd(&deg[dst[i]], 1);
}

__global__ __launch_bounds__(256)
void scanA_kernel(const int* __restrict__ deg, int* __restrict__ psum, int n)
{
    __shared__ int red[256];
    const int t = threadIdx.x;
    const int i = blockIdx.x * 256 + t;
    red[t] = (i < n) ? deg[i] : 0;
    __syncthreads();
    for (int s = 128; s > 0; s >>= 1) {
        if (t < s) red[t] += red[t + s];
        __syncthreads();
    }
    if (t == 0) psum[blockIdx.x] = red[0];
}

__global__ __launch_bounds__(256)
void scanB_kernel(int* __restrict__ psum, int nb)
{
    __shared__ int s[256];
    const int t = threadIdx.x;
    const int v0 = (t < nb) ? psum[t] : 0;
    s[t] = v0;
    __syncthreads();
    for (int d = 1; d < 256; d <<= 1) {
        const int v = (t >= d) ? s[t - d] : 0;
        __syncthreads();
        s[t] += v;
        __syncthreads();
    }
    if (t < nb) psum[t] = s[t] - v0;   // exclusive
}

__global__ __launch_bounds__(256)
void scanC_kernel(const int* __restrict__ deg, const int* __restrict__ psum,
                  int* __restrict__ start, int* __restrict__ cursor, int n)
{
    __shared__ int s[256];
    const int t = threadIdx.x;
    const int i = blockIdx.x * 256 + t;
    const int v0 = (i < n) ? deg[i] : 0;
    s[t] = v0;
    __syncthreads();
    for (int d = 1; d < 256; d <<= 1) {
        const int v = (t >= d) ? s[t - d] : 0;
        __syncthreads();
        s[t] += v;
        __syncthreads();
    }
    const int ex = s[t] - v0 + psum[blockIdx.x];
    if (i < n) { start[i] = ex; cursor[i] = ex; }
}

__global__ __launch_bounds__(256)
void fill_kernel(const int* __restrict__ dst, int* __restrict__ cursor,
                 int* __restrict__ elist, int E)
{
    const int i = blockIdx.x * 256 + threadIdx.x;
    if (i < E) {
        const int d = dst[i];
        const int p = atomicAdd(&cursor[d], 1);
        elist[p] = i;
    }
}

// ---------------------------------------------------------------------------
// Wave-private 3-layer MLP, 32 rows per wave. Block = 4 waves = 128 rows.
// Per-wave 16KB LDS slice: X [32 rows][512B swz]; after layer 1, h1 (8KB)
// aliases X[0:8K] and h2 (8KB) aliases X[8K:16K]. Same swizzle formulas as
// v3 (verified); only row count changed. No intra-MLP barriers.
// Inner loop: load 8 B-frags -> 16 MFMAs (2 row-frags per B-frag).
// ---------------------------------------------------------------------------
template <int NQ, bool IS_EDGE, bool MSG_ATOMIC, bool GATHER>
__global__ __launch_bounds__(256, 2)
void mlp_wave_kernel(const float* __restrict__ feat0,
                     const float* feat1,             // node_feat/msgs (non-gather)
                     const float* __restrict__ gr,
                     const int* __restrict__ srcIdx, const int* __restrict__ dstIdx,
                     const int* __restrict__ seg,
                     const int* __restrict__ gstart, const int* __restrict__ gend,
                     const int* __restrict__ elist,  const float* __restrict__ gsrc,
                     const char* __restrict__ W1f, const float* __restrict__ b1,
                     const char* __restrict__ W2f, const float* __restrict__ b2,
                     const char* __restrict__ W3f, const float* __restrict__ b3,
                     float* out, float* msgs_out, float* comb_rep, int M)
{
    __shared__ char lds[69632];              // 4x16KB wave slices + 4KB comb
    float* combs = (float*)(lds + 65536);

    const int t    = threadIdx.x;
    const int lane = t & 63;
    const int w    = t >> 6;
    const int l15  = lane & 15;
    const int l4   = lane >> 4;
    char* Ws = lds + w * 16384;
    const int base = blockIdx.x * 128 + w * 32;   // wave's first global row

#pragma unroll
    for (int i = 0; i < 4; ++i) combs[i * 256 + t] = 0.f;
    __syncthreads();   // comb ready

    // ---- stage X: 32 rows x NQ*64 f32 -> bf16 swizzled, four 8-row batches ----
    // lane role: source quarter = l4, float4-in-source = l15.
    for (int half = 0; half < 4; ++half) {
        int idx8[8];
#pragma unroll
        for (int i = 0; i < 8; ++i) {
            const int row = base + half * 8 + i;
            int idx = -1;
            if (row < M) {
                if (IS_EDGE) {
                    idx = (l4 == 0) ? row : (l4 == 1) ? srcIdx[row]
                        : (l4 == 2) ? dstIdx[row] : seg[row];
                } else if (GATHER) {
                    idx = (l4 == 0) ? row : (l4 == 2) ? seg[row] : -1;
                } else {
                    idx = (l4 == 0) ? row : (l4 == 1) ? row
                        : (l4 == 2) ? seg[row] : -1;
                }
            }
            idx8[i] = idx;
        }
        float4 v8[8];
#pragma unroll
        for (int i = 0; i < 8; ++i) {
            float4 v = make_float4(0.f, 0.f, 0.f, 0.f);
            if (idx8[i] >= 0) {
                const float* p;
                if (IS_EDGE) {
                    p = (l4 == 0) ? feat0 + (size_t)idx8[i] * 64
                      : (l4 == 3) ? gr    + (size_t)idx8[i] * 64
                      :             feat1 + (size_t)idx8[i] * 64;
                } else if (GATHER) {
                    p = (l4 == 0) ? feat0 + (size_t)idx8[i] * 64
                      :             gr    + (size_t)idx8[i] * 64;
                } else {
                    p = (l4 == 0) ? feat0 + (size_t)idx8[i] * 64
                      : (l4 == 1) ? feat1 + (size_t)idx8[i] * 64
                      :             gr    + (size_t)idx8[i] * 64;
                }
                v = *(const float4*)(p + l15 * 4);
            }
            v8[i] = v;
        }
#pragma unroll
        for (int i = 0; i < 8; ++i) {
            const int row = half * 8 + i;
            union { uint2 u; short s[4]; } pk;
            pk.s[0] = f2bf(v8[i].x); pk.s[1] = f2bf(v8[i].y);
            pk.s[2] = f2bf(v8[i].z); pk.s[3] = f2bf(v8[i].w);
            const int slot = (l4 * 8 + (l15 >> 1)) ^ (row & 7);
            *(uint2*)(Ws + row * 512 + slot * 16 + (l15 & 1) * 8) = pk.u;
        }
    }

    // ---- (node/GATHER) quarter-1 = msgs: f32 gather-sum over incoming edges ----
    if constexpr (GATHER) {
#pragma unroll
        for (int rb = 0; rb < 8; ++rb) {
            const int lrow = rb * 4 + l4;          // 0..31
            const int grow = base + lrow;
            f32x4 m = {0.f, 0.f, 0.f, 0.f};
            if (grow < M) {
                const int s = gstart[grow];
                const int e = gend[grow];
                int j = s;
                for (; j + 1 < e; j += 2) {        // 2-way ILP on the row reads
                    const int e0 = elist[j], e1 = elist[j + 1];
                    const float4 a = *(const float4*)(gsrc + (size_t)e0 * 64 + l15 * 4);
                    const float4 b = *(const float4*)(gsrc + (size_t)e1 * 64 + l15 * 4);
                    m.x += a.x + b.x; m.y += a.y + b.y;
                    m.z += a.z + b.z; m.w += a.w + b.w;
                }
                if (j < e) {
                    const int e0 = elist[j];
                    const float4 a = *(const float4*)(gsrc + (size_t)e0 * 64 + l15 * 4);
                    m.x += a.x; m.y += a.y; m.z += a.z; m.w += a.w;
                }
            }
            union { uint2 u; short s4[4]; } pk;
            pk.s4[0] = f2bf(m.x); pk.s4[1] = f2bf(m.y);
            pk.s4[2] = f2bf(m.z); pk.s4[3] = f2bf(m.w);
            const int slot = (8 + (l15 >> 1)) ^ (lrow & 7);
            *(uint2*)(Ws + lrow * 512 + slot * 16 + (l15 & 1) * 8) = pk.u;
        }
    }

    // ---- layer 1: K = NQ*64, 2 row-frags ----
    constexpr int KF1 = NQ * 2;
    f32x4 acc[2][8];
#pragma unroll
    for (int nf = 0; nf < 8; ++nf) {
        const float bv = b1[nf * 16 + l15];
        acc[0][nf] = f32x4{bv, bv, bv, bv};
        acc[1][nf] = f32x4{bv, bv, bv, bv};
    }
#pragma unroll
    for (int kf = 0; kf < KF1; ++kf) {
        short8 bw[8];
#pragma unroll
        for (int nf = 0; nf < 8; ++nf)
            bw[nf] = *(const short8*)(W1f + ((size_t)(kf * 8 + nf) * 64 + lane) * 16);
        const int slot = (kf * 4 + l4) ^ (l15 & 7);
        short8 a0 = *(short8*)(Ws + l15 * 512 + slot * 16);
        short8 a1 = *(short8*)(Ws + (16 + l15) * 512 + slot * 16);
#pragma unroll
        for (int nf = 0; nf < 8; ++nf) {
            acc[0][nf] = MFMA16(a0, bw[nf], acc[0][nf]);
            acc[1][nf] = MFMA16(a1, bw[nf], acc[1][nf]);
        }
    }
    // relu -> h1 (aliases X[0:8K]; all X reads already issued in-wave)
#pragma unroll
    for (int rf = 0; rf < 2; ++rf)
#pragma unroll
        for (int nf = 0; nf < 8; ++nf)
#pragma unroll
            for (int q = 0; q < 4; ++q) {
                const int row = rf * 16 + l4 * 4 + q;
                const int slot = (nf * 2 + (l15 >> 3)) ^ (row & 7);
                *(short*)(Ws + row * 256 + slot * 16 + (l15 & 7) * 2) =
                    f2bf(fmaxf(acc[rf][nf][q], 0.f));
            }

    // ---- layer 2: K=128 from h1 ----
    f32x4 acc2[2][8];
#pragma unroll
    for (int nf = 0; nf < 8; ++nf) {
        const float bv = b2[nf * 16 + l15];
        acc2[0][nf] = f32x4{bv, bv, bv, bv};
        acc2[1][nf] = f32x4{bv, bv, bv, bv};
    }
#pragma unroll
    for (int kf = 0; kf < 4; ++kf) {
        short8 bw[8];
#pragma unroll
        for (int nf = 0; nf < 8; ++nf)
            bw[nf] = *(const short8*)(W2f + ((size_t)(kf * 8 + nf) * 64 + lane) * 16);
        const int slot = (kf * 4 + l4) ^ (l15 & 7);
        short8 a0 = *(short8*)(Ws + l15 * 256 + slot * 16);
        short8 a1 = *(short8*)(Ws + (16 + l15) * 256 + slot * 16);
#pragma unroll
        for (int nf = 0; nf < 8; ++nf) {
            acc2[0][nf] = MFMA16(a0, bw[nf], acc2[0][nf]);
            acc2[1][nf] = MFMA16(a1, bw[nf], acc2[1][nf]);
        }
    }
    // relu -> h2 at +8192 (aliases X[8K:16K], dead after layer 1)
#pragma unroll
    for (int rf = 0; rf < 2; ++rf)
#pragma unroll
        for (int nf = 0; nf < 8; ++nf)
#pragma unroll
            for (int q = 0; q < 4; ++q) {
                const int row = rf * 16 + l4 * 4 + q;
                const int slot = (nf * 2 + (l15 >> 3)) ^ (row & 7);
                *(short*)(Ws + 8192 + row * 256 + slot * 16 + (l15 & 7) * 2) =
                    f2bf(fmaxf(acc2[rf][nf][q], 0.f));
            }

    // ---- layer 3: K=128 from h2, N=64 ----
    f32x4 acc3[2][4];
#pragma unroll
    for (int nf = 0; nf < 4; ++nf) {
        const float bv = b3[nf * 16 + l15];
        acc3[0][nf] = f32x4{bv, bv, bv, bv};
        acc3[1][nf] = f32x4{bv, bv, bv, bv};
    }
#pragma unroll
    for (int kf = 0; kf < 4; ++kf) {
        short8 bw[4];
#pragma unroll
        for (int nf = 0; nf < 4; ++nf)
            bw[nf] = *(const short8*)(W3f + ((size_t)(kf * 4 + nf) * 64 + lane) * 16);
        const int slot = (kf * 4 + l4) ^ (l15 & 7);
        short8 a0 = *(short8*)(Ws + 8192 + l15 * 256 + slot * 16);
        short8 a1 = *(short8*)(Ws + 8192 + (16 + l15) * 256 + slot * 16);
#pragma unroll
        for (int nf = 0; nf < 4; ++nf) {
            acc3[0][nf] = MFMA16(a0, bw[nf], acc3[0][nf]);
            acc3[1][nf] = MFMA16(a1, bw[nf], acc3[1][nf]);
        }
    }

    // ---- epilogue: store out, (fallback) msgs atomics, LDS comb ----
#pragma unroll
    for (int rf = 0; rf < 2; ++rf)
#pragma unroll
        for (int q = 0; q < 4; ++q) {
            const int grow = base + rf * 16 + l4 * 4 + q;
            if (grow < M) {
                const int g = seg[grow];
                int d = 0;
                if (MSG_ATOMIC) d = dstIdx[grow];
#pragma unroll
                for (int nf = 0; nf < 4; ++nf) {
                    const int col = nf * 16 + l15;
                    const float v = acc3[rf][nf][q];
                    out[(size_t)grow * 64 + col] = v;
                    if constexpr (MSG_ATOMIC)
                        atomicAdd(msgs_out + (size_t)d * 64 + col, v);
                    atomicAdd(&combs[g * 64 + col], v);
                }
            }
        }
    __syncthreads();
    float* rep = comb_rep + (size_t)(blockIdx.x & 63) * 1024;
#pragma unroll
    for (int i = 0; i < 4; ++i) {
        const int s = i * 256 + t;
        atomicAdd(rep + s, combs[s]);
    }
}

// ---------------------------------------------------------------------------
__global__ __launch_bounds__(256)
void reduce_rep_kernel(const float* __restrict__ rep, float* __restrict__ outv)
{
    const int s = blockIdx.x * 256 + threadIdx.x;   // 0..2047
    const int arr = s >> 10, idx = s & 1023;
    const float* p = rep + (size_t)arr * 65536 + idx;
    float v = 0.f;
#pragma unroll 8
    for (int r = 0; r < 64; ++r) v += p[(size_t)r * 1024];
    outv[s] = v;
}

// ---------------------------------------------------------------------------
__global__ __launch_bounds__(256)
void u_kernel(const float* __restrict__ ncomb, const float* __restrict__ ecomb,
              const float* __restrict__ gr,
              const float* __restrict__ W1, const float* __restrict__ b1,
              const float* __restrict__ W2, const float* __restrict__ b2,
              const float* __restrict__ W3, const float* __restrict__ b3,
              float* uout)
{
    __shared__ float X[16 * 192];
    __shared__ float Hs[16 * 128];
    __shared__ float H2s[16 * 128];
    const int t = threadIdx.x;
#pragma unroll
    for (int i = 0; i < 12; ++i) {
        const int idx = i * 256 + t;
        const int g = idx / 192, col = idx % 192;
        float v;
        if      (col < 64)  v = ncomb[g * 64 + col];
        else if (col < 128) v = ecomb[g * 64 + col - 64];
        else                v = gr[g * 64 + col - 128];
        X[idx] = v;
    }
    __syncthreads();
    {
        const int j = t & 127, gb = t >> 7;
        float a[8];
#pragma unroll
        for (int gi = 0; gi < 8; ++gi) a[gi] = b1[j];
        for (int k = 0; k < 192; ++k) {
            const float wv = W1[k * 128 + j];
#pragma unroll
            for (int gi = 0; gi < 8; ++gi) a[gi] += X[(gb + gi * 2) * 192 + k] * wv;
        }
#pragma unroll
        for (int gi = 0; gi < 8; ++gi) Hs[(gb + gi * 2) * 128 + j] = fmaxf(a[gi], 0.f);
    }
    __syncthreads();
    {
        const int j = t & 127, gb = t >> 7;
        float a[8];
#pragma unroll
        for (int gi = 0; gi < 8; ++gi) a[gi] = b2[j];
        for (int k = 0; k < 128; ++k) {
            const float wv = W2[k * 128 + j];
#pragma unroll
            for (int gi = 0; gi < 8; ++gi) a[gi] += Hs[(gb + gi * 2) * 128 + k] * wv;
        }
#pragma unroll
        for (int gi = 0; gi < 8; ++gi) H2s[(gb + gi * 2) * 128 + j] = fmaxf(a[gi], 0.f);
    }
    __syncthreads();
    {
        const int j = t & 63, gb = t >> 6;
        float a[4];
#pragma unroll
        for (int gi = 0; gi < 4; ++gi) a[gi] = b3[j];
        for (int k = 0; k < 128; ++k) {
            const float wv = W3[k * 64 + j];
#pragma unroll
            for (int gi = 0; gi < 4; ++gi) a[gi] += H2s[(gb + gi * 4) * 128 + k] * wv;
        }
#pragma unroll
        for (int gi = 0; gi < 4; ++gi) uout[(gb + gi * 4) * 64 + j] = a[gi];
    }
}

// ---------------------------------------------------------------------------
extern "C" void kernel_launch(void* const* d_in, const int* in_sizes, int n_in,
                              void* d_out, int out_size, void* d_ws, size_t ws_size,
                              hipStream_t stream)
{
    const float* edge_feat = (const float*)d_in[0];
    const float* node_feat = (const float*)d_in[1];
    const float* g_repr    = (const float*)d_in[2];
    const int*   src       = (const int*)d_in[3];
    const int*   dst       = (const int*)d_in[4];
    const int*   e2g       = (const int*)d_in[5];
    const int*   n2g       = (const int*)d_in[6];
    const float* We1 = (const float*)d_in[7];  const float* be1 = (const float*)d_in[8];
    const float* We2 = (const float*)d_in[9];  const float* be2 = (const float*)d_in[10];
    const float* We3 = (const float*)d_in[11]; const float* be3 = (const float*)d_in[12];
    const float* Wn1 = (const float*)d_in[13]; const float* bn1 = (const float*)d_in[14];
    const float* Wn2 = (const float*)d_in[15]; const float* bn2 = (const float*)d_in[16];
    const float* Wn3 = (const float*)d_in[17]; const float* bn3 = (const float*)d_in[18];
    const float* Wu1 = (const float*)d_in[19]; const float* bu1 = (const float*)d_in[20];
    const float* Wu2 = (const float*)d_in[21]; const float* bu2 = (const float*)d_in[22];
    const float* Wu3 = (const float*)d_in[23]; const float* bu3 = (const float*)d_in[24];

    const int E = in_sizes[3];   // 400000
    const int N = in_sizes[6];   // 50000

    float* e_out = (float*)d_out;
    float* n_out = e_out + (size_t)E * 64;
    float* u_out = n_out + (size_t)N * 64;

    // ws layout (bytes):
    //   0        ecomb_rep  64x1024 f32 (256KB)   [memset]
    //   262144   ncomb_rep  64x1024 f32 (256KB)   [memset]
    //   524288   ecomb 1024 f32 | ncomb 1024 f32
    //   532480   bf16 swizzled weights (212992)
    //   745472   deg    N ints                    [memset]
    //   945472   start  N ints
    //   1145472  cursor N ints
    //   1345472  psum   256 ints
    //   1346496  elist  E ints
    char* wsc = (char*)d_ws;
    float* ecomb_rep = (float*)wsc;
    float* ncomb_rep = (float*)(wsc + 262144);
    float* ecomb     = (float*)(wsc + 524288);
    float* ncomb     = ecomb + 1024;
    char*  wf        = wsc + 532480;
    const char* We1f = wf;          const char* We2f = wf + 65536;
    const char* We3f = wf + 98304;  const char* Wn1f = wf + 114688;
    const char* Wn2f = wf + 163840; const char* Wn3f = wf + 196608;
    int* deg    = (int*)(wsc + 745472);
    int* startA = (int*)(wsc + 945472);
    int* cursor = (int*)(wsc + 1145472);
    int* psum   = (int*)(wsc + 1345472);
    int* elist  = (int*)(wsc + 1346496);
    const size_t WS_NEED = 1346496 + (size_t)E * 4;
    const bool csr = (ws_size >= WS_NEED);

    hipMemsetAsync(wsc, 0, 524288, stream);
    prep_weights<<<52, 256, 0, stream>>>(We1, We2, We3, Wn1, Wn2, Wn3, wf);

    if (csr) {
        // ---- build CSR (by dst) ----
        hipMemsetAsync(deg, 0, (size_t)N * 4, stream);
        const int EB = (E + 255) / 256;
        const int NB = (N + 255) / 256;
        hist_kernel <<<EB, 256, 0, stream>>>(dst, deg, E);
        scanA_kernel<<<NB, 256, 0, stream>>>(deg, psum, N);
        scanB_kernel<<<1, 256, 0, stream>>>(psum, NB);
        scanC_kernel<<<NB, 256, 0, stream>>>(deg, psum, startA, cursor, N);
        fill_kernel <<<EB, 256, 0, stream>>>(dst, cursor, elist, E);

        // ---- edge MLP (no msgs atomics) + fused e_comb ----
        mlp_wave_kernel<4, true, false, false><<<(E + 127) / 128, 256, 0, stream>>>(
            edge_feat, node_feat, g_repr, src, dst, e2g,
            nullptr, nullptr, nullptr, nullptr,
            We1f, be1, We2f, be2, We3f, be3, e_out, nullptr, ecomb_rep, E);
        // ---- node MLP with CSR gather of msgs + fused n_comb ----
        mlp_wave_kernel<3, false, false, true><<<(N + 127) / 128, 256, 0, stream>>>(
            node_feat, nullptr, g_repr, nullptr, nullptr, n2g,
            startA, cursor, elist, e_out,
            Wn1f, bn1, Wn2f, bn2, Wn3f, bn3, n_out, nullptr, ncomb_rep, N);
    } else {
        // ---- fallback: atomic scatter path ----
        hipMemsetAsync(n_out, 0, (size_t)N * 64 * sizeof(float), stream);
        mlp_wave_kernel<4, true, true, false><<<(E + 127) / 128, 256, 0, stream>>>(
            edge_feat, node_feat, g_repr, src, dst, e2g,
            nullptr, nullptr, nullptr, nullptr,
            We1f, be1, We2f, be2, We3f, be3, e_out, n_out, ecomb_rep, E);
        mlp_wave_kernel<3, false, false, false><<<(N + 127) / 128, 256, 0, stream>>>(
            node_feat, n_out, g_repr, nullptr, nullptr, n2g,
            nullptr, nullptr, nullptr, nullptr,
            Wn1f, bn1, Wn2f, bn2, Wn3f, bn3, n_out, nullptr, ncomb_rep, N);
    }

    reduce_rep_kernel<<<8, 256, 0, stream>>>(ecomb_rep, ecomb);
    u_kernel<<<1, 256, 0, stream>>>(ncomb, ecomb, g_repr,
                                    Wu1, bu1, Wu2, bu2, Wu3, bu3, u_out);
}

// Round 6
// 366.345 us; speedup vs baseline: 1.4082x; 1.4082x over previous
//
#include <hip/hip_runtime.h>
#include <cstdint>

// GraphNets block v6: weights-in-LDS MFMA MLP, X gathered direct to registers.
// mfma_f32_16x16x32_bf16: A lane l: row=l&15, k=(l>>4)*8+j ; B: col=l&15, same k
// C/D: col=lane&15, row=(lane>>4)*4+reg   [verified v2-v5]

typedef short short8 __attribute__((ext_vector_type(8)));
typedef float f32x4 __attribute__((ext_vector_type(4)));

#define MFMA16(a, b, c) __builtin_amdgcn_mfma_f32_16x16x32_bf16(a, b, c, 0, 0, 0)

__device__ __forceinline__ short f2bf(float x) {
    union { __bf16 b; short s; } u; u.b = (__bf16)x; return u.s;
}
__device__ __forceinline__ short8 pack8(float4 lo, float4 hi) {
    short8 r;
    r[0] = f2bf(lo.x); r[1] = f2bf(lo.y); r[2] = f2bf(lo.z); r[3] = f2bf(lo.w);
    r[4] = f2bf(hi.x); r[5] = f2bf(hi.y); r[6] = f2bf(hi.z); r[7] = f2bf(hi.w);
    return r;
}
__device__ __forceinline__ short8 pack8v(f32x4 lo, f32x4 hi) {
    short8 r;
    r[0] = f2bf(lo[0]); r[1] = f2bf(lo[1]); r[2] = f2bf(lo[2]); r[3] = f2bf(lo[3]);
    r[4] = f2bf(hi[0]); r[5] = f2bf(hi[1]); r[6] = f2bf(hi[2]); r[7] = f2bf(hi[3]);
    return r;
}

// ---------------------------------------------------------------------------
// Weight prep: fp32 [K][N] -> bf16 pre-swizzled B-fragments (frag kf*NF+nf,
// 1024B each, lane-contiguous). Regions are contiguous per-MLP:
// edge = We1|We2|We3 (112KB at off 0), node = Wn1|Wn2|Wn3 (96KB at off 114688).
// ---------------------------------------------------------------------------
__global__ __launch_bounds__(256)
void prep_weights(const float* __restrict__ We1, const float* __restrict__ We2,
                  const float* __restrict__ We3, const float* __restrict__ Wn1,
                  const float* __restrict__ Wn2, const float* __restrict__ Wn3,
                  char* __restrict__ out)
{
    const int fg = blockIdx.x * 4 + (threadIdx.x >> 6);
    if (fg >= 208) return;
    const int lane = threadIdx.x & 63;
    const float* W; int Ncols, f; size_t obase;
    if      (fg < 64)  { W = We1; Ncols = 128; f = fg;       obase = 0;      }
    else if (fg < 96)  { W = We2; Ncols = 128; f = fg - 64;  obase = 65536;  }
    else if (fg < 112) { W = We3; Ncols = 64;  f = fg - 96;  obase = 98304;  }
    else if (fg < 160) { W = Wn1; Ncols = 128; f = fg - 112; obase = 114688; }
    else if (fg < 192) { W = Wn2; Ncols = 128; f = fg - 160; obase = 163840; }
    else               { W = Wn3; Ncols = 64;  f = fg - 192; obase = 196608; }
    const int NF = Ncols >> 4;
    const int kf = f / NF, nf = f - kf * NF;
    const int k0 = kf * 32 + (lane >> 4) * 8;
    const int col = nf * 16 + (lane & 15);
    union { short s[8]; uint4 u; } pk;
#pragma unroll
    for (int j = 0; j < 8; ++j) pk.s[j] = f2bf(W[(size_t)(k0 + j) * Ncols + col]);
    *(uint4*)(out + obase + ((size_t)f * 64 + lane) * 16) = pk.u;
}

// ---------------------------------------------------------------------------
// CSR build (verified v4)
// ---------------------------------------------------------------------------
__global__ __launch_bounds__(256)
void hist_kernel(const int* __restrict__ dst, int* __restrict__ deg, int E)
{
    const int i = blockIdx.x * 256 + threadIdx.x;
    if (i < E) atomicAdd(&deg[dst[i]], 1);
}
__global__ __launch_bounds__(256)
void scanA_kernel(const int* __restrict__ deg, int* __restrict__ psum, int n)
{
    __shared__ int red[256];
    const int t = threadIdx.x;
    const int i = blockIdx.x * 256 + t;
    red[t] = (i < n) ? deg[i] : 0;
    __syncthreads();
    for (int s = 128; s > 0; s >>= 1) {
        if (t < s) red[t] += red[t + s];
        __syncthreads();
    }
    if (t == 0) psum[blockIdx.x] = red[0];
}
__global__ __launch_bounds__(256)
void scanB_kernel(int* __restrict__ psum, int nb)
{
    __shared__ int s[256];
    const int t = threadIdx.x;
    const int v0 = (t < nb) ? psum[t] : 0;
    s[t] = v0;
    __syncthreads();
    for (int d = 1; d < 256; d <<= 1) {
        const int v = (t >= d) ? s[t - d] : 0;
        __syncthreads();
        s[t] += v;
        __syncthreads();
    }
    if (t < nb) psum[t] = s[t] - v0;
}
__global__ __launch_bounds__(256)
void scanC_kernel(const int* __restrict__ deg, const int* __restrict__ psum,
                  int* __restrict__ start, int* __restrict__ cursor, int n)
{
    __shared__ int s[256];
    const int t = threadIdx.x;
    const int i = blockIdx.x * 256 + t;
    const int v0 = (i < n) ? deg[i] : 0;
    s[t] = v0;
    __syncthreads();
    for (int d = 1; d < 256; d <<= 1) {
        const int v = (t >= d) ? s[t - d] : 0;
        __syncthreads();
        s[t] += v;
        __syncthreads();
    }
    const int ex = s[t] - v0 + psum[blockIdx.x];
    if (i < n) { start[i] = ex; cursor[i] = ex; }
}
__global__ __launch_bounds__(256)
void fill_kernel(const int* __restrict__ dst, int* __restrict__ cursor,
                 int* __restrict__ elist, int E)
{
    const int i = blockIdx.x * 256 + threadIdx.x;
    if (i < E) {
        const int d = dst[i];
        const int p = atomicAdd(&cursor[d], 1);
        elist[p] = i;
    }
}

// ---------------------------------------------------------------------------
// Fused MLP, weights resident in LDS. Block = 512 thr = 8 waves, 1 block/CU.
// Each wave owns 16 rows per tile; block tile = 128 rows; grid-stride tiles.
// LDS: [W frags NFRAG KB] [8 x 4KB h slice] [4KB comb].
// X gathered straight to A-fragment registers (no X LDS, no barriers in loop).
// ---------------------------------------------------------------------------
template <int NQ, bool IS_EDGE, bool MSG_ATOMIC, bool GATHER>
__global__ __launch_bounds__(512, 2)
void mlp_fused_kernel(const float* __restrict__ feat0,
                      const float* feat1,
                      const float* __restrict__ gr,
                      const int* __restrict__ srcIdx, const int* __restrict__ dstIdx,
                      const int* __restrict__ seg,
                      const int* __restrict__ gstart, const int* __restrict__ gend,
                      const int* __restrict__ elist,  const float* __restrict__ gsrc,
                      const char* __restrict__ Wsrc,
                      const float* __restrict__ b1, const float* __restrict__ b2,
                      const float* __restrict__ b3,
                      float* out, float* msgs_out, float* comb_rep,
                      int M, int ntiles)
{
    constexpr int KF1   = NQ * 2;                  // layer-1 kf count
    constexpr int NFRAG = KF1 * 8 + 32 + 16;       // W1 + W2 + W3 frags
    constexpr int HOFF  = NFRAG * 1024;
    extern __shared__ char lds[];
    float* combs = (float*)(lds + HOFF + 8 * 4096);

    const int t    = threadIdx.x;
    const int lane = t & 63;
    const int w    = t >> 6;
    const int l15  = lane & 15;
    const int l4   = lane >> 4;
    char* Hs = lds + HOFF + w * 4096;              // wave-private 16x128 bf16

    // ---- stage all weight fragments to LDS once; zero comb ----
    for (int f = t; f < NFRAG * 64; f += 512)
        *(uint4*)(lds + (size_t)f * 16) = *(const uint4*)(Wsrc + (size_t)f * 16);
    for (int i = t; i < 1024; i += 512) combs[i] = 0.f;
    __syncthreads();

    const char* W1l = lds;
    const char* W2l = lds + (size_t)KF1 * 8 * 1024;
    const char* W3l = W2l + 32 * 1024;

    const float bv1 = 0.f; (void)bv1;

    for (int tile = blockIdx.x; tile < ntiles; tile += gridDim.x) {
        const int base = tile * 128 + w * 16;
        const int row  = base + l15;               // this lane's source row
        const bool valid = row < M;

        // ---- indices (one level of the dep chain) ----
        int isrc = 0, idst = 0, ig = 0;
        if (valid) {
            if (IS_EDGE) { isrc = srcIdx[row]; idst = dstIdx[row]; ig = seg[row]; }
            else         { ig = seg[row]; }
        }

        // ---- gather X straight into A-fragment registers ----
        short8 xf[KF1];
#pragma unroll
        for (int kf = 0; kf < KF1; ++kf) {
            const int c = kf >> 1;
            if (GATHER && c == 1) continue;        // msgs handled below
            float4 lo = make_float4(0.f, 0.f, 0.f, 0.f), hi = lo;
            if (valid) {
                const float* p;
                if (IS_EDGE) {
                    p = (c == 0) ? feat0 + (size_t)row  * 64
                      : (c == 1) ? feat1 + (size_t)isrc * 64
                      : (c == 2) ? feat1 + (size_t)idst * 64
                      :            gr    + (size_t)ig   * 64;
                } else if (GATHER) {
                    p = (c == 0) ? feat0 + (size_t)row * 64
                      :            gr    + (size_t)ig  * 64;
                } else {
                    p = (c == 0) ? feat0 + (size_t)row * 64
                      : (c == 1) ? feat1 + (size_t)row * 64
                      :            gr    + (size_t)ig  * 64;
                }
                const int koff = (kf & 1) * 32 + l4 * 8;
                lo = *(const float4*)(p + koff);
                hi = *(const float4*)(p + koff + 4);
            }
            xf[kf] = pack8(lo, hi);
        }
        if constexpr (GATHER) {
            // msgs chunk (c==1 -> kf 2,3): CSR sum of e_out rows, 16 f32/lane
            f32x4 m0 = {0,0,0,0}, m1 = m0, m2 = m0, m3 = m0;
            if (valid) {
                const int s0 = gstart[row], e0 = gend[row];
                for (int j = s0; j < e0; ++j) {
                    const float* er = gsrc + (size_t)elist[j] * 64 + l4 * 8;
                    m0 += *(const f32x4*)(er);
                    m1 += *(const f32x4*)(er + 4);
                    m2 += *(const f32x4*)(er + 32);
                    m3 += *(const f32x4*)(er + 36);
                }
            }
            xf[2] = pack8v(m0, m1);
            xf[3] = pack8v(m2, m3);
        }

        // ---- layer 1: K = NQ*64, bw from LDS ----
        f32x4 acc[8];
#pragma unroll
        for (int nf = 0; nf < 8; ++nf) {
            const float bv = b1[nf * 16 + l15];
            acc[nf] = f32x4{bv, bv, bv, bv};
        }
#pragma unroll
        for (int kf = 0; kf < KF1; ++kf) {
#pragma unroll
            for (int nf = 0; nf < 8; ++nf) {
                short8 bw = *(const short8*)(W1l + ((size_t)(kf * 8 + nf) * 64 + lane) * 16);
                acc[nf] = MFMA16(xf[kf], bw, acc[nf]);
            }
        }
        // relu -> h1 (wave-private; v3-verified swizzle, stride 256B)
#pragma unroll
        for (int nf = 0; nf < 8; ++nf)
#pragma unroll
            for (int q = 0; q < 4; ++q) {
                const int rowL = l4 * 4 + q;
                const int slot = (nf * 2 + (l15 >> 3)) ^ (rowL & 7);
                *(short*)(Hs + rowL * 256 + slot * 16 + (l15 & 7) * 2) =
                    f2bf(fmaxf(acc[nf][q], 0.f));
            }

        // ---- layer 2: K=128 ----
        f32x4 acc2[8];
#pragma unroll
        for (int nf = 0; nf < 8; ++nf) {
            const float bv = b2[nf * 16 + l15];
            acc2[nf] = f32x4{bv, bv, bv, bv};
        }
#pragma unroll
        for (int kf = 0; kf < 4; ++kf) {
            const int slot = (kf * 4 + l4) ^ (l15 & 7);
            short8 a = *(short8*)(Hs + l15 * 256 + slot * 16);
#pragma unroll
            for (int nf = 0; nf < 8; ++nf) {
                short8 bw = *(const short8*)(W2l + ((size_t)(kf * 8 + nf) * 64 + lane) * 16);
                acc2[nf] = MFMA16(a, bw, acc2[nf]);
            }
        }
        // relu -> h2 (aliases h1: all h1 reads precede in program order, in-wave)
#pragma unroll
        for (int nf = 0; nf < 8; ++nf)
#pragma unroll
            for (int q = 0; q < 4; ++q) {
                const int rowL = l4 * 4 + q;
                const int slot = (nf * 2 + (l15 >> 3)) ^ (rowL & 7);
                *(short*)(Hs + rowL * 256 + slot * 16 + (l15 & 7) * 2) =
                    f2bf(fmaxf(acc2[nf][q], 0.f));
            }

        // ---- layer 3: K=128, N=64 ----
        f32x4 acc3[4];
#pragma unroll
        for (int nf = 0; nf < 4; ++nf) {
            const float bv = b3[nf * 16 + l15];
            acc3[nf] = f32x4{bv, bv, bv, bv};
        }
#pragma unroll
        for (int kf = 0; kf < 4; ++kf) {
            const int slot = (kf * 4 + l4) ^ (l15 & 7);
            short8 a = *(short8*)(Hs + l15 * 256 + slot * 16);
#pragma unroll
            for (int nf = 0; nf < 4; ++nf) {
                short8 bw = *(const short8*)(W3l + ((size_t)(kf * 4 + nf) * 64 + lane) * 16);
                acc3[nf] = MFMA16(a, bw, acc3[nf]);
            }
        }

        // ---- epilogue ----
#pragma unroll
        for (int q = 0; q < 4; ++q) {
            const int grow = base + l4 * 4 + q;
            if (grow < M) {
                const int g = seg[grow];
                int d = 0;
                if (MSG_ATOMIC) d = dstIdx[grow];
#pragma unroll
                for (int nf = 0; nf < 4; ++nf) {
                    const int col = nf * 16 + l15;
                    const float v = acc3[nf][q];
                    out[(size_t)grow * 64 + col] = v;
                    if constexpr (MSG_ATOMIC)
                        atomicAdd(msgs_out + (size_t)d * 64 + col, v);
                    atomicAdd(&combs[g * 64 + col], v);
                }
            }
        }
    }

    // ---- flush per-block comb to replica ----
    __syncthreads();
    float* rep = comb_rep + (size_t)(blockIdx.x & 63) * 1024;
    for (int i = t; i < 1024; i += 512) atomicAdd(rep + i, combs[i]);
}

// ---------------------------------------------------------------------------
__global__ __launch_bounds__(256)
void reduce_rep_kernel(const float* __restrict__ rep, float* __restrict__ outv)
{
    const int s = blockIdx.x * 256 + threadIdx.x;   // 0..2047
    const int arr = s >> 10, idx = s & 1023;
    const float* p = rep + (size_t)arr * 65536 + idx;
    float v = 0.f;
#pragma unroll 8
    for (int r = 0; r < 64; ++r) v += p[(size_t)r * 1024];
    outv[s] = v;
}

// ---------------------------------------------------------------------------
__global__ __launch_bounds__(256)
void u_kernel(const float* __restrict__ ncomb, const float* __restrict__ ecomb,
              const float* __restrict__ gr,
              const float* __restrict__ W1, const float* __restrict__ b1,
              const float* __restrict__ W2, const float* __restrict__ b2,
              const float* __restrict__ W3, const float* __restrict__ b3,
              float* uout)
{
    __shared__ float X[16 * 192];
    __shared__ float Hs[16 * 128];
    __shared__ float H2s[16 * 128];
    const int t = threadIdx.x;
#pragma unroll
    for (int i = 0; i < 12; ++i) {
        const int idx = i * 256 + t;
        const int g = idx / 192, col = idx % 192;
        float v;
        if      (col < 64)  v = ncomb[g * 64 + col];
        else if (col < 128) v = ecomb[g * 64 + col - 64];
        else                v = gr[g * 64 + col - 128];
        X[idx] = v;
    }
    __syncthreads();
    {
        const int j = t & 127, gb = t >> 7;
        float a[8];
#pragma unroll
        for (int gi = 0; gi < 8; ++gi) a[gi] = b1[j];
        for (int k = 0; k < 192; ++k) {
            const float wv = W1[k * 128 + j];
#pragma unroll
            for (int gi = 0; gi < 8; ++gi) a[gi] += X[(gb + gi * 2) * 192 + k] * wv;
        }
#pragma unroll
        for (int gi = 0; gi < 8; ++gi) Hs[(gb + gi * 2) * 128 + j] = fmaxf(a[gi], 0.f);
    }
    __syncthreads();
    {
        const int j = t & 127, gb = t >> 7;
        float a[8];
#pragma unroll
        for (int gi = 0; gi < 8; ++gi) a[gi] = b2[j];
        for (int k = 0; k < 128; ++k) {
            const float wv = W2[k * 128 + j];
#pragma unroll
            for (int gi = 0; gi < 8; ++gi) a[gi] += Hs[(gb + gi * 2) * 128 + k] * wv;
        }
#pragma unroll
        for (int gi = 0; gi < 8; ++gi) H2s[(gb + gi * 2) * 128 + j] = fmaxf(a[gi], 0.f);
    }
    __syncthreads();
    {
        const int j = t & 63, gb = t >> 6;
        float a[4];
#pragma unroll
        for (int gi = 0; gi < 4; ++gi) a[gi] = b3[j];
        for (int k = 0; k < 128; ++k) {
            const float wv = W3[k * 64 + j];
#pragma unroll
            for (int gi = 0; gi < 4; ++gi) a[gi] += H2s[(gb + gi * 4) * 128 + k] * wv;
        }
#pragma unroll
        for (int gi = 0; gi < 4; ++gi) uout[(gb + gi * 4) * 64 + j] = a[gi];
    }
}

// ---------------------------------------------------------------------------
extern "C" void kernel_launch(void* const* d_in, const int* in_sizes, int n_in,
                              void* d_out, int out_size, void* d_ws, size_t ws_size,
                              hipStream_t stream)
{
    const float* edge_feat = (const float*)d_in[0];
    const float* node_feat = (const float*)d_in[1];
    const float* g_repr    = (const float*)d_in[2];
    const int*   src       = (const int*)d_in[3];
    const int*   dst       = (const int*)d_in[4];
    const int*   e2g       = (const int*)d_in[5];
    const int*   n2g       = (const int*)d_in[6];
    const float* We1 = (const float*)d_in[7];  const float* be1 = (const float*)d_in[8];
    const float* We2 = (const float*)d_in[9];  const float* be2 = (const float*)d_in[10];
    const float* We3 = (const float*)d_in[11]; const float* be3 = (const float*)d_in[12];
    const float* Wn1 = (const float*)d_in[13]; const float* bn1 = (const float*)d_in[14];
    const float* Wn2 = (const float*)d_in[15]; const float* bn2 = (const float*)d_in[16];
    const float* Wn3 = (const float*)d_in[17]; const float* bn3 = (const float*)d_in[18];
    const float* Wu1 = (const float*)d_in[19]; const float* bu1 = (const float*)d_in[20];
    const float* Wu2 = (const float*)d_in[21]; const float* bu2 = (const float*)d_in[22];
    const float* Wu3 = (const float*)d_in[23]; const float* bu3 = (const float*)d_in[24];

    const int E = in_sizes[3];   // 400000
    const int N = in_sizes[6];   // 50000

    float* e_out = (float*)d_out;
    float* n_out = e_out + (size_t)E * 64;
    float* u_out = n_out + (size_t)N * 64;

    // ws layout (bytes): as v4/v5
    char* wsc = (char*)d_ws;
    float* ecomb_rep = (float*)wsc;
    float* ncomb_rep = (float*)(wsc + 262144);
    float* ecomb     = (float*)(wsc + 524288);
    float* ncomb     = ecomb + 1024;
    char*  wf        = wsc + 532480;
    const char* WEsrc = wf;              // We1|We2|We3  (112 KB)
    const char* WNsrc = wf + 114688;     // Wn1|Wn2|Wn3  (96 KB)
    int* deg    = (int*)(wsc + 745472);
    int* startA = (int*)(wsc + 945472);
    int* cursor = (int*)(wsc + 1145472);
    int* psum   = (int*)(wsc + 1345472);
    int* elist  = (int*)(wsc + 1346496);
    const size_t WS_NEED = 1346496 + (size_t)E * 4;
    const bool csr = (ws_size >= WS_NEED);

    constexpr int SH_E = (112 + 32 + 4) * 1024;   // 151552
    constexpr int SH_N = (96 + 32 + 4) * 1024;    // 135168

    hipMemsetAsync(wsc, 0, 524288, stream);
    prep_weights<<<52, 256, 0, stream>>>(We1, We2, We3, Wn1, Wn2, Wn3, wf);

    const int etiles = (E + 127) / 128;
    const int ntiles = (N + 127) / 128;

    if (csr) {
        hipMemsetAsync(deg, 0, (size_t)N * 4, stream);
        const int EB = (E + 255) / 256;
        const int NB = (N + 255) / 256;
        hist_kernel <<<EB, 256, 0, stream>>>(dst, deg, E);
        scanA_kernel<<<NB, 256, 0, stream>>>(deg, psum, N);
        scanB_kernel<<<1, 256, 0, stream>>>(psum, NB);
        scanC_kernel<<<NB, 256, 0, stream>>>(deg, psum, startA, cursor, N);
        fill_kernel <<<EB, 256, 0, stream>>>(dst, cursor, elist, E);

        auto ek = mlp_fused_kernel<4, true, false, false>;
        auto nk = mlp_fused_kernel<3, false, false, true>;
        hipFuncSetAttribute((const void*)ek,
                            hipFuncAttributeMaxDynamicSharedMemorySize, SH_E);
        hipFuncSetAttribute((const void*)nk,
                            hipFuncAttributeMaxDynamicSharedMemorySize, SH_N);

        ek<<<256, 512, SH_E, stream>>>(
            edge_feat, node_feat, g_repr, src, dst, e2g,
            nullptr, nullptr, nullptr, nullptr,
            WEsrc, be1, be2, be3, e_out, nullptr, ecomb_rep, E, etiles);
        nk<<<256, 512, SH_N, stream>>>(
            node_feat, nullptr, g_repr, nullptr, nullptr, n2g,
            startA, cursor, elist, e_out,
            WNsrc, bn1, bn2, bn3, n_out, nullptr, ncomb_rep, N, ntiles);
    } else {
        hipMemsetAsync(n_out, 0, (size_t)N * 64 * sizeof(float), stream);
        auto ek = mlp_fused_kernel<4, true, true, false>;
        auto nk = mlp_fused_kernel<3, false, false, false>;
        hipFuncSetAttribute((const void*)ek,
                            hipFuncAttributeMaxDynamicSharedMemorySize, SH_E);
        hipFuncSetAttribute((const void*)nk,
                            hipFuncAttributeMaxDynamicSharedMemorySize, SH_N);
        ek<<<256, 512, SH_E, stream>>>(
            edge_feat, node_feat, g_repr, src, dst, e2g,
            nullptr, nullptr, nullptr, nullptr,
            WEsrc, be1, be2, be3, e_out, n_out, ecomb_rep, E, etiles);
        nk<<<256, 512, SH_N, stream>>>(
            node_feat, n_out, g_repr, nullptr, nullptr, n2g,
            nullptr, nullptr, nullptr, nullptr,
            WNsrc, bn1, bn2, bn3, n_out, nullptr, ncomb_rep, N, ntiles);
    }

    reduce_rep_kernel<<<8, 256, 0, stream>>>(ecomb_rep, ecomb);
    u_kernel<<<1, 256, 0, stream>>>(ncomb, ecomb, g_repr,
                                    Wu1, bu1, Wu2, bu2, Wu3, bu3, u_out);
}